// Round 5
// baseline (307.004 us; speedup 1.0000x reference)
//
#include <hip/hip_runtime.h>

// (B,S,HID,NH) = (2,2048,1024,16), HD=64
#define S_LEN 2048
#define HIDN  1024
#define NHEAD 16
#define HDIM  64
#define MROWS 4096   // B*S
#define KDIM  1024
#define NDIM  1024

typedef __attribute__((ext_vector_type(8))) short bf16x8;  // 8 bf16 = 4 VGPRs
typedef __attribute__((ext_vector_type(4))) short bf16x4;  // 4 bf16 = 2 VGPRs
typedef __attribute__((ext_vector_type(4))) float f32x4;

static __device__ __forceinline__ ushort f2bf(float f) {
    unsigned int u = __float_as_uint(f);
    u = (u + 0x7fffu + ((u >> 16) & 1u)) >> 16;  // RNE
    return (ushort)u;
}
static __device__ __forceinline__ float bf2f(ushort u) {
    return __uint_as_float(((unsigned int)u) << 16);
}

// async global->LDS, 16B per lane. LDS dest must be (wave-uniform base + lane*16).
static __device__ __forceinline__ void gload16(const ushort* g, ushort* l) {
    __builtin_amdgcn_global_load_lds(
        (const __attribute__((address_space(1))) unsigned int*)g,
        (__attribute__((address_space(3))) unsigned int*)l, 16, 0, 0);
}

// physical XCD id of the CU this wave runs on (gfx940+ hwreg, verified MI355X)
static __device__ __forceinline__ int get_xcd() {
    int x;
    asm volatile("s_getreg_b32 %0, hwreg(HW_REG_XCC_ID, 0, 4)" : "=s"(x));
    return x & 7;
}

// ---------------------------------------------------------------------------
// Fused prep: 7 fp32->bf16 tensor converts + RoPE tables + attn work-queue
// counter reset (8 per-XCD queues), one launch.
// ---------------------------------------------------------------------------
__global__ __launch_bounds__(256) void prep_kernel(
    const float* __restrict__ q, const float* __restrict__ k,
    const float* __restrict__ v, const float* __restrict__ Wq,
    const float* __restrict__ Wk, const float* __restrict__ Wv,
    const float* __restrict__ Wo,
    ushort* __restrict__ qb, ushort* __restrict__ kb, ushort* __restrict__ vb,
    ushort* __restrict__ Wqb, ushort* __restrict__ Wkb, ushort* __restrict__ Wvb,
    ushort* __restrict__ Wob,
    float* __restrict__ rc, float* __restrict__ rs, int* __restrict__ ctr)
{
    const long Q4 = (long)MROWS * KDIM / 4;   // 1048576
    const long W4 = (long)NDIM * KDIM / 4;    // 262144
    if (blockIdx.x < 16384) {
        long i = (long)blockIdx.x * 256 + threadIdx.x;
        const float* src; ushort* dst; long off;
        if (i < Q4)          { src = q; dst = qb; off = i; }
        else if (i < 2 * Q4) { src = k; dst = kb; off = i - Q4; }
        else if (i < 3 * Q4) { src = v; dst = vb; off = i - 2 * Q4; }
        else {
            long t = i - 3 * Q4;
            int wsel = (int)(t >> 18);        // W4 = 2^18
            off = t & (W4 - 1);
            src = (wsel == 0) ? Wq : (wsel == 1) ? Wk : (wsel == 2) ? Wv : Wo;
            dst = (wsel == 0) ? Wqb : (wsel == 1) ? Wkb : (wsel == 2) ? Wvb : Wob;
        }
        float4 vv = ((const float4*)src)[off];
        ushort4 o;
        o.x = f2bf(vv.x); o.y = f2bf(vv.y); o.z = f2bf(vv.z); o.w = f2bf(vv.w);
        ((ushort4*)dst)[off] = o;
    } else {
        int idx = (blockIdx.x - 16384) * 256 + threadIdx.x;  // 65536
        if (idx < 8) ctr[idx] = 0;            // reset the 8 per-XCD queues
        int s  = idx >> 5;
        int jp = idx & 31;
        float theta = expf(-(float)(2 * jp) * (9.210340371976184f / 64.0f));
        float ang = (float)s * theta;
        float sv, cv;
        sincosf(ang, &sv, &cv);
        rc[idx] = cv;
        rs[idx] = sv;
    }
}

// ---------------------------------------------------------------------------
// Shared GEMM mainloop, 128x128 tile (m97 structure): acc += A_tile x W_tile^T
// over K. BK=64, 4 waves each owning a 64x64 quadrant (4x4 acc frags),
// 32 MFMA per wave per K-step. Matched XOR granule swizzle -> 0 conflicts.
// ---------------------------------------------------------------------------
static __device__ __forceinline__ void gemm_mainloop128(
    const ushort* __restrict__ A, const ushort* __restrict__ W,
    ushort* As, ushort* Bs, f32x4 (&acc)[4][4],
    int m0, int n0, int tid)
{
    const int lane = tid & 63, wid = tid >> 6;
    const int wm = wid & 1, wn = wid >> 1;
    const int quad = lane >> 4, l15 = lane & 15;

    for (int k0 = 0; k0 < KDIM; k0 += 64) {
        __syncthreads();
#pragma unroll
        for (int rr = 0; rr < 4; ++rr) {
            int sidx = tid + rr * 256;
            int row = sidx >> 3;
            int g = (sidx & 7) ^ (row & 7);
            gload16(A + (size_t)(m0 + row) * KDIM + k0 + g * 8, As + sidx * 8);
            gload16(W + (size_t)(n0 + row) * KDIM + k0 + g * 8, Bs + sidx * 8);
        }
        __syncthreads();

#pragma unroll
        for (int ks = 0; ks < 2; ++ks) {
            bf16x8 af[4], bfr[4];
#pragma unroll
            for (int i = 0; i < 4; ++i) {
                int row = wm * 64 + i * 16 + l15;
                int gg = ((ks << 2) | quad) ^ (row & 7);
                af[i] = *(const bf16x8*)&As[row * 64 + gg * 8];
            }
#pragma unroll
            for (int j = 0; j < 4; ++j) {
                int row = wn * 64 + j * 16 + l15;
                int gg = ((ks << 2) | quad) ^ (row & 7);
                bfr[j] = *(const bf16x8*)&Bs[row * 64 + gg * 8];
            }
#pragma unroll
            for (int i = 0; i < 4; ++i)
#pragma unroll
                for (int j = 0; j < 4; ++j)
                    acc[i][j] = __builtin_amdgcn_mfma_f32_16x16x32_bf16(
                        af[i], bfr[j], acc[i][j], 0, 0, 0);
        }
    }
}

// ---------------------------------------------------------------------------
// Fused QKV projections, gridDim = (32, 8, 3).
// z==2 (V): role-swapped staging (A=Wv, B=v).
// ---------------------------------------------------------------------------
__global__ __launch_bounds__(256, 3) void gemm_qkv(
    const ushort* __restrict__ qb, const ushort* __restrict__ kb,
    const ushort* __restrict__ vb,
    const ushort* __restrict__ Wqb, const ushort* __restrict__ Wkb,
    const ushort* __restrict__ Wvb,
    ushort* __restrict__ Qh, ushort* __restrict__ Kh, ushort* __restrict__ Vt,
    const float* __restrict__ rc, const float* __restrict__ rs)
{
    __shared__ __align__(16) ushort As[128 * 64];
    __shared__ __align__(16) ushort Bs[128 * 64];

    const int tid = threadIdx.x;
    const int lane = tid & 63, wid = tid >> 6;
    const int wm = wid & 1, wn = wid >> 1;
    const int quad = lane >> 4, l15 = lane & 15;
    const int z = blockIdx.z;

    const ushort* A; const ushort* W; int m0, n0;
    if (z == 2) {   // V: A = weights (1024 rows), B = activations (4096 rows)
        m0 = (int)blockIdx.y * 128;      // 8 tiles over weight rows
        n0 = (int)blockIdx.x * 128;      // 32 tiles over activation rows
        A = Wvb; W = vb;
    } else {
        m0 = blockIdx.x * 128; n0 = blockIdx.y * 128;
        A = (z == 0) ? qb : kb;
        W = (z == 0) ? Wqb : Wkb;
    }

    f32x4 acc[4][4];
#pragma unroll
    for (int i = 0; i < 4; ++i)
#pragma unroll
        for (int j = 0; j < 4; ++j) acc[i][j] = 0.0f;

    gemm_mainloop128(A, W, As, Bs, acc, m0, n0, tid);

    if (z != 2) {   // Q or K: RoPE (+ scale fold for Q); m=(b,s), n=(h,d)
        ushort* out = (z == 0) ? Qh : Kh;
        const float scale = (z == 0) ? 0.18033688011112042f : 1.0f;  // 0.125*log2e
#pragma unroll
        for (int i = 0; i < 4; ++i)
#pragma unroll
            for (int j = 0; j < 4; ++j)
#pragma unroll
                for (int r = 0; r < 4; ++r) {
                    int m = m0 + wm * 64 + i * 16 + quad * 4 + r;
                    int n = n0 + wn * 64 + j * 16 + l15;
                    float v = acc[i][j][r];
                    int b = m >> 11, s = m & (S_LEN - 1);
                    int h = n >> 6, d = n & 63;
                    int pidx = s * 32 + (d >> 1);
                    float cv = rc[pidx], sv = rs[pidx];
                    float partner = __shfl_xor(v, 1);
                    v = (d & 1) ? (v * cv + partner * sv)
                                : (v * cv - partner * sv);
                    out[((size_t)((b * NHEAD + h) * S_LEN + s)) * HDIM + d] =
                        f2bf(v * scale);
                }
    } else {        // V: m=(h,d) over 1024, n=(b,s) over 4096
#pragma unroll
        for (int i = 0; i < 4; ++i)
#pragma unroll
            for (int j = 0; j < 4; ++j)
#pragma unroll
                for (int r = 0; r < 4; ++r) {
                    int m = m0 + wm * 64 + i * 16 + quad * 4 + r;
                    int n = n0 + wn * 64 + j * 16 + l15;
                    int h = m >> 6, d = m & 63;
                    int b = n >> 11, s = n & (S_LEN - 1);
                    Vt[((size_t)((b * NHEAD + h) * HDIM + d)) * S_LEN + s] =
                        f2bf(acc[i][j][r]);
                }
    }
}

// ---------------------------------------------------------------------------
// Output projection with FUSED combine. 64x128 tile, grid dim3(64,8) = 512
// blocks = 2 blocks/CU. DO NOT shrink the grid without changing the tile.
// ---------------------------------------------------------------------------
__global__ __launch_bounds__(256) void gemm_out(
    const ushort* __restrict__ O0, const ushort* __restrict__ O1,
    const float* __restrict__ L0, const float* __restrict__ L1,
    const ushort* __restrict__ W, float* __restrict__ out)
{
    __shared__ __align__(16) ushort As[64 * 64];
    __shared__ __align__(16) ushort Bs[128 * 64];

    const int tid = threadIdx.x;
    const int lane = tid & 63, wid = tid >> 6;
    const int wm = wid & 1, wn = wid >> 1;
    const int quad = lane >> 4, l15 = lane & 15;
    const int m0 = blockIdx.x * 64, n0 = blockIdx.y * 128;

    f32x4 acc[2][4];
#pragma unroll
    for (int i = 0; i < 2; ++i)
#pragma unroll
        for (int j = 0; j < 4; ++j) acc[i][j] = 0.0f;

    for (int k0 = 0; k0 < KDIM; k0 += 64) {
        const int h = k0 >> 6;
        bf16x8 a0[2], a1[2];
        float li[2];
#pragma unroll
        for (int rr = 0; rr < 2; ++rr) {
            int sidx = tid + rr * 256;
            int row = sidx >> 3;
            int g = (sidx & 7) ^ (row & 7);
            int m = m0 + row, bb = m >> 11, s = m & (S_LEN - 1);
            size_t rowO = (size_t)(bb * NHEAD + h) * S_LEN + s;
            a0[rr] = *(const bf16x8*)(O0 + rowO * HDIM + g * 8);
            a1[rr] = *(const bf16x8*)(O1 + rowO * HDIM + g * 8);
            li[rr] = __builtin_amdgcn_rcpf(L0[rowO] + L1[rowO]);
        }
        __syncthreads();
#pragma unroll
        for (int rr = 0; rr < 2; ++rr) {
            int sidx = tid + rr * 256;
            bf16x8 packed;
#pragma unroll
            for (int e = 0; e < 8; ++e) {
                float f = (bf2f((ushort)a0[rr][e]) + bf2f((ushort)a1[rr][e])) * li[rr];
                packed[e] = (short)(__float_as_uint(f) >> 16);  // trunc pack
            }
            *(bf16x8*)&As[sidx * 8] = packed;
        }
#pragma unroll
        for (int rr = 0; rr < 4; ++rr) {
            int sidx = tid + rr * 256;
            int row = sidx >> 3;
            int g = (sidx & 7) ^ (row & 7);
            gload16(W + (size_t)(n0 + row) * KDIM + k0 + g * 8, Bs + sidx * 8);
        }
        __syncthreads();

#pragma unroll
        for (int ks = 0; ks < 2; ++ks) {
            bf16x8 af[2], bfr[4];
#pragma unroll
            for (int i = 0; i < 2; ++i) {
                int row = wm * 32 + i * 16 + l15;
                int gg = ((ks << 2) | quad) ^ (row & 7);
                af[i] = *(const bf16x8*)&As[row * 64 + gg * 8];
            }
#pragma unroll
            for (int j = 0; j < 4; ++j) {
                int row = wn * 64 + j * 16 + l15;
                int gg = ((ks << 2) | quad) ^ (row & 7);
                bfr[j] = *(const bf16x8*)&Bs[row * 64 + gg * 8];
            }
#pragma unroll
            for (int i = 0; i < 2; ++i)
#pragma unroll
                for (int j = 0; j < 4; ++j)
                    acc[i][j] = __builtin_amdgcn_mfma_f32_16x16x32_bf16(
                        af[i], bfr[j], acc[i][j], 0, 0, 0);
        }
    }

#pragma unroll
    for (int i = 0; i < 2; ++i)
#pragma unroll
        for (int j = 0; j < 4; ++j)
#pragma unroll
            for (int r = 0; r < 4; ++r) {
                int m = m0 + wm * 32 + i * 16 + quad * 4 + r;
                int n = n0 + wn * 64 + j * 16 + l15;
                out[(size_t)m * NDIM + n] = acc[i][j][r];
            }
}

// ---------------------------------------------------------------------------
// Split-K MFMA causal flash attention (r2 compute body, QBLK=64) with
// PER-XCD WORK QUEUES + LPT:
//   r4 post-mortem: a single global queue balanced work but destroyed XCD L2
//   locality (FETCH 13.5 -> 70-95 MB, became fetch-bound at 60 us). Fix: 8
//   queues, one per physical XCD; queue x holds only units with h%8 == x
//   (4 (b,h) pairs = 4 MB K/V = one L2). Each block asks the HARDWARE where
//   it runs via s_getreg(HW_REG_XCC_ID) — zero assumptions about block->XCD
//   mapping — and drains its own queue; work-stealing over the other 7
//   queues guarantees completion regardless.
//   Grid 1024 = 4 blocks/CU (16 waves), ~2 units/block; slots are ordered
//   big-first (t<32 = 9..16-tile units), so greedy pulling = LPT: one big +
//   one small ~ 17 tiles/block, concurrency stays 4/CU for the whole kernel
//   (r2's static 8/CU decayed to a lone-block 16-tile tail, Occ 32%).
// Unit decode: slot s in [0,256): t = s>>2 (r2 big-first map), b = s&1,
//   h = q + ((s&2)<<2). seg/y/qt/lo/hi exactly as r2.
// Dataflow per unit (verified r2, conflicts=0): S^T = K Q^T; p = exp2 packs
//   in-register to 16x16x16 B-frags; O^T = V^T P. K: gload_lds + 16B-granule
//   XOR swizzle. V: reg-staged, 8B-slot swizzle, next-tile V prefetch.
// ---------------------------------------------------------------------------
__global__ __launch_bounds__(256) void attn_mfma(
    const ushort* __restrict__ Qh, const ushort* __restrict__ Kh,
    const ushort* __restrict__ Vt,
    ushort* __restrict__ O0, ushort* __restrict__ O1,
    float* __restrict__ L0, float* __restrict__ L1,
    int* __restrict__ ctr)
{
    __shared__ __align__(16) ushort Ks[64 * 64];
    __shared__ __align__(16) ushort Vs[64 * 64];
    __shared__ int s_id;

    const int tid = threadIdx.x;
    const int lane = tid & 63, w = tid >> 6;
    const int quad = lane >> 4, l15 = lane & 15;
    const int xcd = get_xcd();

    // thread-invariant staging geometry (hoisted out of the unit loop)
    int krow[2], kgsw[2], vsp[2], vwa[2][2];
#pragma unroll
    for (int rr = 0; rr < 2; ++rr) {
        int sidx = tid + rr * 256;
        int row = sidx >> 3;
        krow[rr] = row;
        kgsw[rr] = (sidx & 7) ^ (row & 7);   // 16B-granule XOR swizzle (K)
        vsp[rr]  = sidx & 7;                 // 16B chunk = 8B slots 2sp,2sp+1
        vwa[rr][0] = row * 64 + ((2 * vsp[rr])     ^ (row & 15)) * 4;
        vwa[rr][1] = row * 64 + ((2 * vsp[rr] + 1) ^ (row & 15)) * 4;
    }

    for (int attempt = 0; attempt < 8; ++attempt) {
        const int q = (xcd + attempt) & 7;   // own queue first, then steal
        for (;;) {
            __syncthreads();                 // protect s_id reuse
            if (tid == 0) s_id = atomicAdd(&ctr[q], 1);
            __syncthreads();
            const int slot = s_id;
            if (slot >= 256) break;

            // unit decode: big-first t, 4 bh per queue
            const int t = slot >> 2;                  // [0,64) big-first
            const int b = slot & 1;
            const int h = q + ((slot & 2) << 2);      // q or q+8
            int seg, y;
            if (t < 32) { seg = (t & 1) ? 0 : 1; y = (t & 1) ? 31 - (t >> 1) : (t >> 1); }
            else { int u = t - 32; seg = (u & 1) ? 0 : 1;
                   y = (u & 1) ? 15 - (u >> 1) : 16 + (u >> 1); }

            const int qt = seg ? (31 - y) : y;
            const int lo = seg ? ((33 - y) >> 1) : 0;
            const int hi = seg ? (32 - y) : ((y + 2) >> 1);
            const int q0 = qt * 64;
            const size_t hoff = (size_t)(b * NHEAD + h) * S_LEN * HDIM;

            // Q B-frags (read once): B[n=q=l15][k=quad*8+e]
            bf16x8 qf[2];
#pragma unroll
            for (int ks = 0; ks < 2; ++ks)
                qf[ks] = *(const bf16x8*)(Qh + hoff +
                    (size_t)(q0 + w * 16 + l15) * HDIM + ks * 32 + quad * 8);

            f32x4 Oa[4];   // O^T acc: Oa[mt][r] = O[q=myq][d = mt*16+quad*4+r]
#pragma unroll
            for (int mt = 0; mt < 4; ++mt) Oa[mt] = 0.0f;
            float lsum = 0.f;
            const int myq = q0 + w * 16 + l15;   // this lane's q-column

            // per-unit staging pointers
            const ushort* kg[2]; const ushort* vgr[2];
#pragma unroll
            for (int rr = 0; rr < 2; ++rr) {
                kg[rr]  = Kh + hoff + (size_t)(lo * 64 + krow[rr]) * HDIM + kgsw[rr] * 8;
                vgr[rr] = Vt + hoff + (size_t)krow[rr] * S_LEN + lo * 64 + vsp[rr] * 8;
            }

            // prologue: prefetch first V tile into registers (skip empty units)
            bf16x8 vv[2];
            if (lo < hi) {
#pragma unroll
                for (int rr = 0; rr < 2; ++rr) { vv[rr] = *(const bf16x8*)vgr[rr]; vgr[rr] += 64; }
            }

            for (int kt = lo; kt < hi; ++kt) {
                const int k0 = kt * 64;
                const bool diag = (kt == qt);      // wave-uniform
                __syncthreads();
#pragma unroll
                for (int rr = 0; rr < 2; ++rr) {
                    // V: regs (ready since last drain) -> swizzled 8B LDS slots
                    *(bf16x4*)&Vs[vwa[rr][0]] =
                        __builtin_shufflevector(vv[rr], vv[rr], 0, 1, 2, 3);
                    *(bf16x4*)&Vs[vwa[rr][1]] =
                        __builtin_shufflevector(vv[rr], vv[rr], 4, 5, 6, 7);
                    // K: async global->LDS
                    gload16(kg[rr], Ks + (tid + rr * 256) * 8);
                    kg[rr] += 64 * HDIM;
                }
                // prefetch NEXT V tile; guard avoids OOB on last tile
                if (kt + 1 < hi) {
#pragma unroll
                    for (int rr = 0; rr < 2; ++rr) { vv[rr] = *(const bf16x8*)vgr[rr]; vgr[rr] += 64; }
                }
                __syncthreads();

                // S^T = K Q^T: A = K frags (rows=keys), B = Q frags (cols=q)
                f32x4 Sa[4];
#pragma unroll
                for (int jm = 0; jm < 4; ++jm) Sa[jm] = 0.0f;
#pragma unroll
                for (int ks = 0; ks < 2; ++ks) {
                    const int p = ((ks << 2) | quad) ^ (l15 & 7);
                    bf16x8 kf[4];
#pragma unroll
                    for (int jm = 0; jm < 4; ++jm)
                        kf[jm] = *(const bf16x8*)&Ks[(jm * 16 + l15) * 64 + p * 8];
#pragma unroll
                    for (int jm = 0; jm < 4; ++jm)
                        Sa[jm] = __builtin_amdgcn_mfma_f32_16x16x32_bf16(
                            kf[jm], qf[ks], Sa[jm], 0, 0, 0);
                }

                // p = exp2(S^T); diag mask; pack in-register to 16x16x16 B-frags
                bf16x4 pb[4];
#pragma unroll
                for (int jm = 0; jm < 4; ++jm) {
#pragma unroll
                    for (int r = 0; r < 4; ++r) {
                        float pv = __builtin_amdgcn_exp2f(Sa[jm][r]);
                        if (diag) {
                            int key = k0 + jm * 16 + quad * 4 + r;
                            if (key > myq) pv = 0.f;
                        }
                        lsum += pv;
                        pb[jm][r] = (short)(__float_as_uint(pv) >> 16);
                    }
                }

                // O^T += V^T P : A-frag[m=d(l15)][k=quad*4+e] via ds_read_b64
                // of the 8B slot (jm*4+quad) ^ l15 — conflict-free
#pragma unroll
                for (int jm = 0; jm < 4; ++jm) {
                    const int slot2 = (((jm * 4 + quad) ^ l15) << 2);
#pragma unroll
                    for (int mt = 0; mt < 4; ++mt) {
                        bf16x4 vf = *(const bf16x4*)&Vs[(mt * 16 + l15) * 64 + slot2];
                        Oa[mt] = __builtin_amdgcn_mfma_f32_16x16x16bf16_1k(
                            vf, pb[jm], Oa[mt], 0, 0, 0);
                    }
                }
            }

            // full row-sum: reduce per-lane partials across the 4 quads
            lsum += __shfl_xor(lsum, 16);
            lsum += __shfl_xor(lsum, 32);

            // partial write (zeros for empty units): lane owns q-row myq
            ushort* Op = seg ? O1 : O0;
            float*  Lp = seg ? L1 : L0;
            const size_t row = (size_t)(b * NHEAD + h) * S_LEN + myq;
#pragma unroll
            for (int mt = 0; mt < 4; ++mt) {
                ushort4 o;
                o.x = f2bf(Oa[mt][0]); o.y = f2bf(Oa[mt][1]);
                o.z = f2bf(Oa[mt][2]); o.w = f2bf(Oa[mt][3]);
                *(ushort4*)&Op[row * HDIM + mt * 16 + quad * 4] = o;
            }
            if (quad == 0) Lp[row] = lsum;
        }
    }
}

// ---------------------------------------------------------------------------
extern "C" void kernel_launch(void* const* d_in, const int* in_sizes, int n_in,
                              void* d_out, int out_size, void* d_ws, size_t ws_size,
                              hipStream_t stream) {
    const float* qf  = (const float*)d_in[0];
    const float* kf  = (const float*)d_in[1];
    const float* vf  = (const float*)d_in[2];
    // d_in[3] = mask (deterministic causal) — unused
    const float* Wqf = (const float*)d_in[4];
    const float* Wkf = (const float*)d_in[5];
    const float* Wvf = (const float*)d_in[6];
    const float* Wof = (const float*)d_in[7];
    float* out = (float*)d_out;

    char* wsp = (char*)d_ws;
    int* ctr = (int*)wsp;               wsp += 256;   // 8 per-XCD queue counters
    float* rc = (float*)wsp;            wsp += 65536 * 4;
    float* rs = (float*)wsp;            wsp += 65536 * 4;
    ushort* qb  = (ushort*)wsp;         wsp += (size_t)MROWS * KDIM * 2;
    ushort* kb  = (ushort*)wsp;         wsp += (size_t)MROWS * KDIM * 2;
    ushort* vb  = (ushort*)wsp;         wsp += (size_t)MROWS * KDIM * 2;
    ushort* Wqb = (ushort*)wsp;         wsp += (size_t)NDIM * KDIM * 2;
    ushort* Wkb = (ushort*)wsp;         wsp += (size_t)NDIM * KDIM * 2;
    ushort* Wvb = (ushort*)wsp;         wsp += (size_t)NDIM * KDIM * 2;
    ushort* Wob = (ushort*)wsp;         wsp += (size_t)NDIM * KDIM * 2;
    ushort* Qh  = (ushort*)wsp;         wsp += (size_t)MROWS * HIDN * 2;
    ushort* Kh  = (ushort*)wsp;         wsp += (size_t)MROWS * HIDN * 2;
    ushort* Vt  = (ushort*)wsp;

    // Attention partial buffers ALIAS qb/kb/vb (dead after gemm_qkv):
    ushort* O0 = qb;                    // 8 MB bf16, 65536 rows x 64
    ushort* O1 = kb;                    // 8 MB
    float*  L0 = (float*)vb;            // 256 KB fp32
    float*  L1 = (float*)vb + 65536;    // 256 KB

    prep_kernel<<<16640, 256, 0, stream>>>(qf, kf, vf, Wqf, Wkf, Wvf, Wof,
                                           qb, kb, vb, Wqb, Wkb, Wvb, Wob,
                                           rc, rs, ctr);

    gemm_qkv<<<dim3(32, 8, 3), 256, 0, stream>>>(
        qb, kb, vb, Wqb, Wkb, Wvb, Qh, Kh, Vt, rc, rs);

    attn_mfma<<<1024, 256, 0, stream>>>(Qh, Kh, Vt, O0, O1, L0, L1, ctr);

    gemm_out<<<dim3(64, 8), 256, 0, stream>>>(O0, O1, L0, L1, Wob, out);
}

// Round 6
// 204.865 us; speedup vs baseline: 1.4986x; 1.4986x over previous
//
#include <hip/hip_runtime.h>

// (B,S,HID,NH) = (2,2048,1024,16), HD=64
#define S_LEN 2048
#define HIDN  1024
#define NHEAD 16
#define HDIM  64
#define MROWS 4096   // B*S
#define KDIM  1024
#define NDIM  1024

typedef __attribute__((ext_vector_type(8))) short bf16x8;  // 8 bf16 = 4 VGPRs
typedef __attribute__((ext_vector_type(4))) short bf16x4;  // 4 bf16 = 2 VGPRs
typedef __attribute__((ext_vector_type(4))) float f32x4;

static __device__ __forceinline__ ushort f2bf(float f) {
    unsigned int u = __float_as_uint(f);
    u = (u + 0x7fffu + ((u >> 16) & 1u)) >> 16;  // RNE
    return (ushort)u;
}
static __device__ __forceinline__ float bf2f(ushort u) {
    return __uint_as_float(((unsigned int)u) << 16);
}

// async global->LDS, 16B per lane. LDS dest must be (wave-uniform base + lane*16).
static __device__ __forceinline__ void gload16(const ushort* g, ushort* l) {
    __builtin_amdgcn_global_load_lds(
        (const __attribute__((address_space(1))) unsigned int*)g,
        (__attribute__((address_space(3))) unsigned int*)l, 16, 0, 0);
}

// ---------------------------------------------------------------------------
// Fused prep: 7 fp32->bf16 tensor converts + RoPE tables, one launch.
// ---------------------------------------------------------------------------
__global__ __launch_bounds__(256) void prep_kernel(
    const float* __restrict__ q, const float* __restrict__ k,
    const float* __restrict__ v, const float* __restrict__ Wq,
    const float* __restrict__ Wk, const float* __restrict__ Wv,
    const float* __restrict__ Wo,
    ushort* __restrict__ qb, ushort* __restrict__ kb, ushort* __restrict__ vb,
    ushort* __restrict__ Wqb, ushort* __restrict__ Wkb, ushort* __restrict__ Wvb,
    ushort* __restrict__ Wob,
    float* __restrict__ rc, float* __restrict__ rs)
{
    const long Q4 = (long)MROWS * KDIM / 4;   // 1048576
    const long W4 = (long)NDIM * KDIM / 4;    // 262144
    if (blockIdx.x < 16384) {
        long i = (long)blockIdx.x * 256 + threadIdx.x;
        const float* src; ushort* dst; long off;
        if (i < Q4)          { src = q; dst = qb; off = i; }
        else if (i < 2 * Q4) { src = k; dst = kb; off = i - Q4; }
        else if (i < 3 * Q4) { src = v; dst = vb; off = i - 2 * Q4; }
        else {
            long t = i - 3 * Q4;
            int wsel = (int)(t >> 18);        // W4 = 2^18
            off = t & (W4 - 1);
            src = (wsel == 0) ? Wq : (wsel == 1) ? Wk : (wsel == 2) ? Wv : Wo;
            dst = (wsel == 0) ? Wqb : (wsel == 1) ? Wkb : (wsel == 2) ? Wvb : Wob;
        }
        float4 vv = ((const float4*)src)[off];
        ushort4 o;
        o.x = f2bf(vv.x); o.y = f2bf(vv.y); o.z = f2bf(vv.z); o.w = f2bf(vv.w);
        ((ushort4*)dst)[off] = o;
    } else {
        int idx = (blockIdx.x - 16384) * 256 + threadIdx.x;  // 65536
        int s  = idx >> 5;
        int jp = idx & 31;
        float theta = expf(-(float)(2 * jp) * (9.210340371976184f / 64.0f));
        float ang = (float)s * theta;
        float sv, cv;
        sincosf(ang, &sv, &cv);
        rc[idx] = cv;
        rs[idx] = sv;
    }
}

// ---------------------------------------------------------------------------
// Shared GEMM mainloop, 128x128 tile (m97 structure): acc += A_tile x W_tile^T
// over K. BK=64, 4 waves each owning a 64x64 quadrant (4x4 acc frags),
// 32 MFMA per wave per K-step. Matched XOR granule swizzle -> 0 conflicts.
// Grid 768 blocks = 3 blocks/CU; __launch_bounds__(256,3) caps VGPR.
// ---------------------------------------------------------------------------
static __device__ __forceinline__ void gemm_mainloop128(
    const ushort* __restrict__ A, const ushort* __restrict__ W,
    ushort* As, ushort* Bs, f32x4 (&acc)[4][4],
    int m0, int n0, int tid)
{
    const int lane = tid & 63, wid = tid >> 6;
    const int wm = wid & 1, wn = wid >> 1;
    const int quad = lane >> 4, l15 = lane & 15;

    for (int k0 = 0; k0 < KDIM; k0 += 64) {
        __syncthreads();
#pragma unroll
        for (int rr = 0; rr < 4; ++rr) {
            int sidx = tid + rr * 256;
            int row = sidx >> 3;
            int g = (sidx & 7) ^ (row & 7);
            gload16(A + (size_t)(m0 + row) * KDIM + k0 + g * 8, As + sidx * 8);
            gload16(W + (size_t)(n0 + row) * KDIM + k0 + g * 8, Bs + sidx * 8);
        }
        __syncthreads();

#pragma unroll
        for (int ks = 0; ks < 2; ++ks) {
            bf16x8 af[4], bfr[4];
#pragma unroll
            for (int i = 0; i < 4; ++i) {
                int row = wm * 64 + i * 16 + l15;
                int gg = ((ks << 2) | quad) ^ (row & 7);
                af[i] = *(const bf16x8*)&As[row * 64 + gg * 8];
            }
#pragma unroll
            for (int j = 0; j < 4; ++j) {
                int row = wn * 64 + j * 16 + l15;
                int gg = ((ks << 2) | quad) ^ (row & 7);
                bfr[j] = *(const bf16x8*)&Bs[row * 64 + gg * 8];
            }
#pragma unroll
            for (int i = 0; i < 4; ++i)
#pragma unroll
                for (int j = 0; j < 4; ++j)
                    acc[i][j] = __builtin_amdgcn_mfma_f32_16x16x32_bf16(
                        af[i], bfr[j], acc[i][j], 0, 0, 0);
        }
    }
}

// ---------------------------------------------------------------------------
// Fused QKV projections, gridDim = (32, 8, 3).
// z==2 (V): role-swapped staging (A=Wv, B=v).
// ---------------------------------------------------------------------------
__global__ __launch_bounds__(256, 3) void gemm_qkv(
    const ushort* __restrict__ qb, const ushort* __restrict__ kb,
    const ushort* __restrict__ vb,
    const ushort* __restrict__ Wqb, const ushort* __restrict__ Wkb,
    const ushort* __restrict__ Wvb,
    ushort* __restrict__ Qh, ushort* __restrict__ Kh, ushort* __restrict__ Vt,
    const float* __restrict__ rc, const float* __restrict__ rs)
{
    __shared__ __align__(16) ushort As[128 * 64];
    __shared__ __align__(16) ushort Bs[128 * 64];

    const int tid = threadIdx.x;
    const int lane = tid & 63, wid = tid >> 6;
    const int wm = wid & 1, wn = wid >> 1;
    const int quad = lane >> 4, l15 = lane & 15;
    const int z = blockIdx.z;

    const ushort* A; const ushort* W; int m0, n0;
    if (z == 2) {   // V: A = weights (1024 rows), B = activations (4096 rows)
        m0 = (int)blockIdx.y * 128;      // 8 tiles over weight rows
        n0 = (int)blockIdx.x * 128;      // 32 tiles over activation rows
        A = Wvb; W = vb;
    } else {
        m0 = blockIdx.x * 128; n0 = blockIdx.y * 128;
        A = (z == 0) ? qb : kb;
        W = (z == 0) ? Wqb : Wkb;
    }

    f32x4 acc[4][4];
#pragma unroll
    for (int i = 0; i < 4; ++i)
#pragma unroll
        for (int j = 0; j < 4; ++j) acc[i][j] = 0.0f;

    gemm_mainloop128(A, W, As, Bs, acc, m0, n0, tid);

    if (z != 2) {   // Q or K: RoPE (+ scale fold for Q); m=(b,s), n=(h,d)
        ushort* out = (z == 0) ? Qh : Kh;
        const float scale = (z == 0) ? 0.18033688011112042f : 1.0f;  // 0.125*log2e
#pragma unroll
        for (int i = 0; i < 4; ++i)
#pragma unroll
            for (int j = 0; j < 4; ++j)
#pragma unroll
                for (int r = 0; r < 4; ++r) {
                    int m = m0 + wm * 64 + i * 16 + quad * 4 + r;
                    int n = n0 + wn * 64 + j * 16 + l15;
                    float v = acc[i][j][r];
                    int b = m >> 11, s = m & (S_LEN - 1);
                    int h = n >> 6, d = n & 63;
                    int pidx = s * 32 + (d >> 1);
                    float cv = rc[pidx], sv = rs[pidx];
                    float partner = __shfl_xor(v, 1);
                    v = (d & 1) ? (v * cv + partner * sv)
                                : (v * cv - partner * sv);
                    out[((size_t)((b * NHEAD + h) * S_LEN + s)) * HDIM + d] =
                        f2bf(v * scale);
                }
    } else {        // V: m=(h,d) over 1024, n=(b,s) over 4096
#pragma unroll
        for (int i = 0; i < 4; ++i)
#pragma unroll
            for (int j = 0; j < 4; ++j)
#pragma unroll
                for (int r = 0; r < 4; ++r) {
                    int m = m0 + wm * 64 + i * 16 + quad * 4 + r;
                    int n = n0 + wn * 64 + j * 16 + l15;
                    int h = m >> 6, d = m & 63;
                    int b = n >> 11, s = n & (S_LEN - 1);
                    Vt[((size_t)((b * NHEAD + h) * HDIM + d)) * S_LEN + s] =
                        f2bf(acc[i][j][r]);
                }
    }
}

// ---------------------------------------------------------------------------
// Output projection with FUSED combine. 64x128 tile, grid dim3(64,8) = 512
// blocks = 2 blocks/CU. DO NOT shrink the grid without changing the tile.
// ---------------------------------------------------------------------------
__global__ __launch_bounds__(256) void gemm_out(
    const ushort* __restrict__ O0, const ushort* __restrict__ O1,
    const float* __restrict__ L0, const float* __restrict__ L1,
    const ushort* __restrict__ W, float* __restrict__ out)
{
    __shared__ __align__(16) ushort As[64 * 64];
    __shared__ __align__(16) ushort Bs[128 * 64];

    const int tid = threadIdx.x;
    const int lane = tid & 63, wid = tid >> 6;
    const int wm = wid & 1, wn = wid >> 1;
    const int quad = lane >> 4, l15 = lane & 15;
    const int m0 = blockIdx.x * 64, n0 = blockIdx.y * 128;

    f32x4 acc[2][4];
#pragma unroll
    for (int i = 0; i < 2; ++i)
#pragma unroll
        for (int j = 0; j < 4; ++j) acc[i][j] = 0.0f;

    for (int k0 = 0; k0 < KDIM; k0 += 64) {
        const int h = k0 >> 6;
        bf16x8 a0[2], a1[2];
        float li[2];
#pragma unroll
        for (int rr = 0; rr < 2; ++rr) {
            int sidx = tid + rr * 256;
            int row = sidx >> 3;
            int g = (sidx & 7) ^ (row & 7);
            int m = m0 + row, bb = m >> 11, s = m & (S_LEN - 1);
            size_t rowO = (size_t)(bb * NHEAD + h) * S_LEN + s;
            a0[rr] = *(const bf16x8*)(O0 + rowO * HDIM + g * 8);
            a1[rr] = *(const bf16x8*)(O1 + rowO * HDIM + g * 8);
            li[rr] = __builtin_amdgcn_rcpf(L0[rowO] + L1[rowO]);
        }
        __syncthreads();
#pragma unroll
        for (int rr = 0; rr < 2; ++rr) {
            int sidx = tid + rr * 256;
            bf16x8 packed;
#pragma unroll
            for (int e = 0; e < 8; ++e) {
                float f = (bf2f((ushort)a0[rr][e]) + bf2f((ushort)a1[rr][e])) * li[rr];
                packed[e] = (short)(__float_as_uint(f) >> 16);  // trunc pack
            }
            *(bf16x8*)&As[sidx * 8] = packed;
        }
#pragma unroll
        for (int rr = 0; rr < 4; ++rr) {
            int sidx = tid + rr * 256;
            int row = sidx >> 3;
            int g = (sidx & 7) ^ (row & 7);
            gload16(W + (size_t)(n0 + row) * KDIM + k0 + g * 8, Bs + sidx * 8);
        }
        __syncthreads();

#pragma unroll
        for (int ks = 0; ks < 2; ++ks) {
            bf16x8 af[2], bfr[4];
#pragma unroll
            for (int i = 0; i < 2; ++i) {
                int row = wm * 32 + i * 16 + l15;
                int gg = ((ks << 2) | quad) ^ (row & 7);
                af[i] = *(const bf16x8*)&As[row * 64 + gg * 8];
            }
#pragma unroll
            for (int j = 0; j < 4; ++j) {
                int row = wn * 64 + j * 16 + l15;
                int gg = ((ks << 2) | quad) ^ (row & 7);
                bfr[j] = *(const bf16x8*)&Bs[row * 64 + gg * 8];
            }
#pragma unroll
            for (int i = 0; i < 2; ++i)
#pragma unroll
                for (int j = 0; j < 4; ++j)
                    acc[i][j] = __builtin_amdgcn_mfma_f32_16x16x32_bf16(
                        af[i], bfr[j], acc[i][j], 0, 0, 0);
        }
    }

#pragma unroll
    for (int i = 0; i < 2; ++i)
#pragma unroll
        for (int j = 0; j < 4; ++j)
#pragma unroll
            for (int r = 0; r < 4; ++r) {
                int m = m0 + wm * 32 + i * 16 + quad * 4 + r;
                int n = n0 + wn * 64 + j * 16 + l15;
                out[(size_t)m * NDIM + n] = acc[i][j][r];
            }
}

// ---------------------------------------------------------------------------
// Split-K MFMA causal flash attention — r2-EXACT structure (verified 40.4 us,
// conflicts 0, FETCH 13.5 MB), grid 2048 = 8 blocks/CU static.
// r3/r4/r5 scheduling experiments (bigger blocks, global queue, per-XCD
// queues) all regressed (48/60/138 us): the static consecutive-id map is
// already per-CU balanced under round-robin dispatch (32 consecutive ids
// share one tile-count class -> each CU gets one block of each size), and
// 8 blocks/CU provides the phase diversity that hides per-tile latency.
// ONE new change vs r2: s_setprio(1) around the MFMA clusters (T5): null for
// barrier-lockstep GEMM (m190) but +4-7% for attn built from independent
// blocks at different phases (m191) — exactly this kernel's shape.
// ---------------------------------------------------------------------------
__global__ __launch_bounds__(256) void attn_mfma(
    const ushort* __restrict__ Qh, const ushort* __restrict__ Kh,
    const ushort* __restrict__ Vt,
    ushort* __restrict__ O0, ushort* __restrict__ O1,
    float* __restrict__ L0, float* __restrict__ L1)
{
    __shared__ __align__(16) ushort Ks[64 * 64];
    __shared__ __align__(16) ushort Vs[64 * 64];

    const int tid = threadIdx.x;
    const int lane = tid & 63, w = tid >> 6;
    const int quad = lane >> 4, l15 = lane & 15;
    const int id = blockIdx.x;
    const int h = id & 15, b = (id >> 4) & 1, t = id >> 5;   // t in [0,64)

    // big-first ordering: t<32 = 9..16-tile units, t>=32 = 0..8-tile units
    int seg, y;
    if (t < 32) { seg = (t & 1) ? 0 : 1; y = (t & 1) ? 31 - (t >> 1) : (t >> 1); }
    else { int u = t - 32; seg = (u & 1) ? 0 : 1;
           y = (u & 1) ? 15 - (u >> 1) : 16 + (u >> 1); }

    const int qt = seg ? (31 - y) : y;
    const int lo = seg ? ((33 - y) >> 1) : 0;
    const int hi = seg ? (32 - y) : ((y + 2) >> 1);
    const int q0 = qt * 64;
    const size_t hoff = (size_t)(b * NHEAD + h) * S_LEN * HDIM;

    // Q B-frags (read once): B[n=q=l15][k=quad*8+e]
    bf16x8 qf[2];
#pragma unroll
    for (int ks = 0; ks < 2; ++ks)
        qf[ks] = *(const bf16x8*)(Qh + hoff +
            (size_t)(q0 + w * 16 + l15) * HDIM + ks * 32 + quad * 8);

    f32x4 Oa[4];   // O^T acc: Oa[mt][r] = O[q=myq][d = mt*16 + quad*4 + r]
#pragma unroll
    for (int mt = 0; mt < 4; ++mt) Oa[mt] = 0.0f;
    float lsum = 0.f;
    const int myq = q0 + w * 16 + l15;   // this lane's q-column

    // K staging: gload_lds with 16B-granule XOR swizzle (conflict-free)
    const ushort* kg[2];
    // V staging: per-thread global srcs (linear) + fixed swizzled LDS dests
    const ushort* vgr[2];
    int vwa[2][2];
#pragma unroll
    for (int rr = 0; rr < 2; ++rr) {
        int sidx = tid + rr * 256;
        int row = sidx >> 3;
        int gsw = (sidx & 7) ^ (row & 7);  // XOR swizzle of 16B granules (K)
        kg[rr] = Kh + hoff + (size_t)(lo * 64 + row) * HDIM + gsw * 8;
        int sp = sidx & 7;                 // 16B chunk = global 8B slots 2sp,2sp+1
        vgr[rr] = Vt + hoff + (size_t)row * S_LEN + lo * 64 + sp * 8;
        vwa[rr][0] = row * 64 + ((2 * sp)     ^ (row & 15)) * 4;
        vwa[rr][1] = row * 64 + ((2 * sp + 1) ^ (row & 15)) * 4;
    }

    // prologue: prefetch first V tile into registers (skip empty units)
    bf16x8 vv[2];
    if (lo < hi) {
#pragma unroll
        for (int rr = 0; rr < 2; ++rr) { vv[rr] = *(const bf16x8*)vgr[rr]; vgr[rr] += 64; }
    }

    for (int kt = lo; kt < hi; ++kt) {
        const int k0 = kt * 64;
        const bool diag = (kt == qt);      // wave-uniform
        __syncthreads();
#pragma unroll
        for (int rr = 0; rr < 2; ++rr) {
            // V: regs (ready since last drain) -> swizzled 8B LDS slots
            *(bf16x4*)&Vs[vwa[rr][0]] =
                __builtin_shufflevector(vv[rr], vv[rr], 0, 1, 2, 3);
            *(bf16x4*)&Vs[vwa[rr][1]] =
                __builtin_shufflevector(vv[rr], vv[rr], 4, 5, 6, 7);
            // K: async global->LDS
            gload16(kg[rr], Ks + (tid + rr * 256) * 8);
            kg[rr] += 64 * HDIM;
        }
        // prefetch NEXT V tile; wave-uniform guard avoids OOB on last tile
        if (kt + 1 < hi) {
#pragma unroll
            for (int rr = 0; rr < 2; ++rr) { vv[rr] = *(const bf16x8*)vgr[rr]; vgr[rr] += 64; }
        }
        __syncthreads();

        // S^T = K Q^T: A = K frags (rows=keys), B = Q frags (cols=q)
        f32x4 Sa[4];
#pragma unroll
        for (int jm = 0; jm < 4; ++jm) Sa[jm] = 0.0f;
        __builtin_amdgcn_s_setprio(1);
#pragma unroll
        for (int ks = 0; ks < 2; ++ks) {
            const int p = ((ks << 2) | quad) ^ (l15 & 7);
            bf16x8 kf[4];
#pragma unroll
            for (int jm = 0; jm < 4; ++jm)
                kf[jm] = *(const bf16x8*)&Ks[(jm * 16 + l15) * 64 + p * 8];
#pragma unroll
            for (int jm = 0; jm < 4; ++jm)
                Sa[jm] = __builtin_amdgcn_mfma_f32_16x16x32_bf16(
                    kf[jm], qf[ks], Sa[jm], 0, 0, 0);
        }
        __builtin_amdgcn_s_setprio(0);

        // p = exp2(S^T); diag mask; pack in-register to 16x16x16 B-frags
        bf16x4 pb[4];
#pragma unroll
        for (int jm = 0; jm < 4; ++jm) {
#pragma unroll
            for (int r = 0; r < 4; ++r) {
                float pv = __builtin_amdgcn_exp2f(Sa[jm][r]);
                if (diag) {
                    int key = k0 + jm * 16 + quad * 4 + r;
                    if (key > myq) pv = 0.f;
                }
                lsum += pv;
                pb[jm][r] = (short)(__float_as_uint(pv) >> 16);
            }
        }

        // O^T += V^T P : A-frag[m=d(l15)][k=quad*4+e] via ds_read_b64 of the
        // 8B slot (jm*4+quad) ^ l15 — conflict-free per 16-lane phase
        __builtin_amdgcn_s_setprio(1);
#pragma unroll
        for (int jm = 0; jm < 4; ++jm) {
            const int slot = (((jm * 4 + quad) ^ l15) << 2);
#pragma unroll
            for (int mt = 0; mt < 4; ++mt) {
                bf16x4 vf = *(const bf16x4*)&Vs[(mt * 16 + l15) * 64 + slot];
                Oa[mt] = __builtin_amdgcn_mfma_f32_16x16x16bf16_1k(vf, pb[jm],
                                                                   Oa[mt], 0, 0, 0);
            }
        }
        __builtin_amdgcn_s_setprio(0);
    }

    // full row-sum: reduce per-lane partials across the 4 quads
    lsum += __shfl_xor(lsum, 16);
    lsum += __shfl_xor(lsum, 32);

    // partial write (zeros for empty units): lane owns q-row myq
    ushort* Op = seg ? O1 : O0;
    float*  Lp = seg ? L1 : L0;
    const size_t row = (size_t)(b * NHEAD + h) * S_LEN + myq;
#pragma unroll
    for (int mt = 0; mt < 4; ++mt) {
        ushort4 o;
        o.x = f2bf(Oa[mt][0]); o.y = f2bf(Oa[mt][1]);
        o.z = f2bf(Oa[mt][2]); o.w = f2bf(Oa[mt][3]);
        *(ushort4*)&Op[row * HDIM + mt * 16 + quad * 4] = o;
    }
    if (quad == 0) Lp[row] = lsum;
}

// ---------------------------------------------------------------------------
extern "C" void kernel_launch(void* const* d_in, const int* in_sizes, int n_in,
                              void* d_out, int out_size, void* d_ws, size_t ws_size,
                              hipStream_t stream) {
    const float* qf  = (const float*)d_in[0];
    const float* kf  = (const float*)d_in[1];
    const float* vf  = (const float*)d_in[2];
    // d_in[3] = mask (deterministic causal) — unused
    const float* Wqf = (const float*)d_in[4];
    const float* Wkf = (const float*)d_in[5];
    const float* Wvf = (const float*)d_in[6];
    const float* Wof = (const float*)d_in[7];
    float* out = (float*)d_out;

    char* wsp = (char*)d_ws;
    float* rc = (float*)wsp;            wsp += 65536 * 4;
    float* rs = (float*)wsp;            wsp += 65536 * 4;
    ushort* qb  = (ushort*)wsp;         wsp += (size_t)MROWS * KDIM * 2;
    ushort* kb  = (ushort*)wsp;         wsp += (size_t)MROWS * KDIM * 2;
    ushort* vb  = (ushort*)wsp;         wsp += (size_t)MROWS * KDIM * 2;
    ushort* Wqb = (ushort*)wsp;         wsp += (size_t)NDIM * KDIM * 2;
    ushort* Wkb = (ushort*)wsp;         wsp += (size_t)NDIM * KDIM * 2;
    ushort* Wvb = (ushort*)wsp;         wsp += (size_t)NDIM * KDIM * 2;
    ushort* Wob = (ushort*)wsp;         wsp += (size_t)NDIM * KDIM * 2;
    ushort* Qh  = (ushort*)wsp;         wsp += (size_t)MROWS * HIDN * 2;
    ushort* Kh  = (ushort*)wsp;         wsp += (size_t)MROWS * HIDN * 2;
    ushort* Vt  = (ushort*)wsp;

    // Attention partial buffers ALIAS qb/kb/vb (dead after gemm_qkv):
    ushort* O0 = qb;                    // 8 MB bf16, 65536 rows x 64
    ushort* O1 = kb;                    // 8 MB
    float*  L0 = (float*)vb;            // 256 KB fp32
    float*  L1 = (float*)vb + 65536;    // 256 KB

    prep_kernel<<<16640, 256, 0, stream>>>(qf, kf, vf, Wqf, Wkf, Wvf, Wof,
                                           qb, kb, vb, Wqb, Wkb, Wvb, Wob, rc, rs);

    gemm_qkv<<<dim3(32, 8, 3), 256, 0, stream>>>(
        qb, kb, vb, Wqb, Wkb, Wvb, Qh, Kh, Vt, rc, rs);

    attn_mfma<<<2048, 256, 0, stream>>>(Qh, Kh, Vt, O0, O1, L0, L1);

    gemm_out<<<dim3(64, 8), 256, 0, stream>>>(O0, O1, L0, L1, Wob, out);
}